// Round 1
// baseline (1021.924 us; speedup 1.0000x reference)
//
#include <hip/hip_runtime.h>
#include <hip/hip_bf16.h>
#include <math.h>

// Problem constants (from reference): T=1024 time steps, S=512 sequences,
// D=32 features, K=64 states. K == wavefront size (64) -> lane = state.
#define TT 1024
#define SS 512
#define DD 32
#define KK 64

#define LOG2PI_F 1.8378770664093453f

// One wave (64 lanes) per sequence. Lane k owns state k:
//  - column k of the transition matrix in 64 VGPRs
//  - mean/inv-covar row k in 64 VGPRs
// Per time step: emission prob on the fly (wave-uniform x loads), dot of
// LDS-held alpha with the register-held A column, wave-reduce for the
// normalizer, accumulate log(denom).
__global__ __launch_bounds__(64) void hmm_forward(
    const float* __restrict__ data,      // [T,S,D]
    const float* __restrict__ initial,   // [K]
    const float* __restrict__ trans,     // [K,K] row-stochastic
    const float* __restrict__ means,     // [K,D]
    const float* __restrict__ covars,    // [K,D]
    float* __restrict__ out_alpha,       // [S,K]
    float* __restrict__ seq_logd)        // [S] workspace
{
    const int s = blockIdx.x;
    const int k = threadIdx.x;

    // ---- per-lane constants ----
    float acol[KK];                      // A[j][k] for all j
#pragma unroll
    for (int j = 0; j < KK; ++j) acol[j] = trans[j * KK + k];

    float w[DD], m[DD];
    float c0 = DD * LOG2PI_F;            // sum log covars + D*log(2pi)
#pragma unroll
    for (int d = 0; d < DD; ++d) {
        float c = covars[k * DD + d];
        w[d] = 1.0f / c;
        m[d] = means[k * DD + d];
        c0 += __logf(c);
    }
    const float init_k = initial[k];

    __shared__ float alpha_sh[KK];

    float logd_acc = 0.0f;
    float alpha_k = 0.0f;

    for (int t = 0; t < TT; ++t) {
        // ---- emission prob for (t, s, k) ----
        // wave-uniform address: all lanes read the same 128 B of x
        const float4* xp = (const float4*)(data + ((size_t)t * SS + s) * DD);
        float q0 = 0.0f, q1 = 0.0f;
#pragma unroll
        for (int d4 = 0; d4 < DD / 4; ++d4) {
            float4 x = xp[d4];
            float t0 = x.x - m[4 * d4 + 0]; q0 = fmaf(w[4 * d4 + 0] * t0, t0, q0);
            float t1 = x.y - m[4 * d4 + 1]; q1 = fmaf(w[4 * d4 + 1] * t1, t1, q1);
            float t2 = x.z - m[4 * d4 + 2]; q0 = fmaf(w[4 * d4 + 2] * t2, t2, q0);
            float t3 = x.w - m[4 * d4 + 3]; q1 = fmaf(w[4 * d4 + 3] * t3, t3, q1);
        }
        float logp = -0.5f * (q0 + q1 + c0);
        float p = __expf(logp);

        // ---- recursion ----
        float a;
        if (t == 0) {
            a = init_k * p;
        } else {
            float s0 = 0.0f, s1 = 0.0f, s2 = 0.0f, s3 = 0.0f;
            const float4* ash = (const float4*)alpha_sh;
#pragma unroll
            for (int j4 = 0; j4 < KK / 4; ++j4) {
                float4 av = ash[j4];
                s0 = fmaf(av.x, acol[4 * j4 + 0], s0);
                s1 = fmaf(av.y, acol[4 * j4 + 1], s1);
                s2 = fmaf(av.z, acol[4 * j4 + 2], s2);
                s3 = fmaf(av.w, acol[4 * j4 + 3], s3);
            }
            a = p * ((s0 + s1) + (s2 + s3));
        }

        // ---- normalizer: sum over the 64 lanes ----
        float den = a;
#pragma unroll
        for (int off = 32; off > 0; off >>= 1)
            den += __shfl_xor(den, off, 64);

        alpha_k = a * (1.0f / den);
        logd_acc += __logf(den);

        // publish alpha for next step (single wave: barrier is an
        // LDS-ordering fence; cheap)
        alpha_sh[k] = alpha_k;
        __syncthreads();
    }

    out_alpha[(size_t)s * KK + k] = alpha_k;
    if (k == 0) seq_logd[s] = logd_acc;
}

// nll = -sum_s logd_s  (since alpha rows are normalized,
// logsumexp(log(alpha)+log_denom) == log_denom exactly)
__global__ __launch_bounds__(256) void reduce_nll(
    const float* __restrict__ seq_logd, float* __restrict__ out_nll)
{
    float v = 0.0f;
    for (int j = threadIdx.x; j < SS; j += 256) v += seq_logd[j];
#pragma unroll
    for (int off = 32; off > 0; off >>= 1)
        v += __shfl_xor(v, off, 64);
    __shared__ float sh[4];
    if ((threadIdx.x & 63) == 0) sh[threadIdx.x >> 6] = v;
    __syncthreads();
    if (threadIdx.x == 0)
        out_nll[0] = -(sh[0] + sh[1] + sh[2] + sh[3]);
}

extern "C" void kernel_launch(void* const* d_in, const int* in_sizes, int n_in,
                              void* d_out, int out_size, void* d_ws, size_t ws_size,
                              hipStream_t stream) {
    const float* data    = (const float*)d_in[0];  // [T,S,D]
    const float* initial = (const float*)d_in[1];  // [K]
    const float* trans   = (const float*)d_in[2];  // [K,K]
    const float* means   = (const float*)d_in[3];  // [K,D]
    const float* covars  = (const float*)d_in[4];  // [K,D]

    float* out_alpha = (float*)d_out;              // [S,K] = 32768 floats
    float* out_nll   = (float*)d_out + (size_t)SS * KK;  // 1 float
    float* seq_logd  = (float*)d_ws;               // [S] floats scratch

    hmm_forward<<<SS, 64, 0, stream>>>(data, initial, trans, means, covars,
                                       out_alpha, seq_logd);
    reduce_nll<<<1, 256, 0, stream>>>(seq_logd, out_nll);
}